// Round 1
// 132.758 us; speedup vs baseline: 1.0155x; 1.0155x over previous
//
#include <hip/hip_runtime.h>

#define BB 32
#define NN 256
#define NF 16

typedef _Float16 half4 __attribute__((ext_vector_type(4)));
typedef float f32x4 __attribute__((ext_vector_type(4)));

// ws layout (floats): ping-pong x/h/su/sv (R8 layout, proven)
#define X0_OFF 0
#define X1_OFF 32768
#define H0_OFF 65536
#define H1_OFF 196608
#define SU0_OFF 327680
#define SV0_OFF 458752
#define SU1_OFF 589824
#define SV1_OFF 720896
#define SU2_OFF 851968
#define SV2_OFF 983040

__device__ __forceinline__ float dot4(float4 a, float4 b, float acc) {
    acc = fmaf(a.x, b.x, acc); acc = fmaf(a.y, b.y, acc);
    acc = fmaf(a.z, b.z, acc); acc = fmaf(a.w, b.w, acc);
    return acc;
}

// init (R13): 512 blocks x 256 thr; block = 16 nodes. Phase 1: thread (n,f)
// computes h = relu(c*W_in+b_in) -> LDS + h0. Phase 2: thread (n,k) computes
// u,v with 32 LDS-broadcast FMAs.
__global__ __launch_bounds__(256)
void init_kernel(const float* __restrict__ xs, const float* __restrict__ charges,
                 const float* __restrict__ W_in, const float* __restrict__ b_in,
                 const float* __restrict__ We1, const float* __restrict__ be1,
                 float* __restrict__ x0, float* __restrict__ h0,
                 float* __restrict__ su0, float* __restrict__ sv0) {
    __shared__ float sWs[256], sWd[256];
    __shared__ __align__(16) float sh[16][NF];
    __shared__ float sb1[NF];
    const int tid = threadIdx.x;
    const size_t n0 = (size_t)blockIdx.x * 16;      // first node of this block
    const int nl = tid >> 4;                        // local node 0..15
    const int k  = tid & 15;                        // feature / k index
    sWs[tid] = We1[tid];
    sWd[tid] = We1[256 + tid];
    if (tid < NF) sb1[tid] = be1[tid];
    {
        const float c = charges[n0 + nl];
        const float hf = fmaxf(fmaf(c, W_in[k], b_in[k]), 0.f);
        sh[nl][k] = hf;
        h0[(n0 + nl) * NF + k] = hf;
    }
    if (tid < 64) {
        const int jd = tid >> 2, q = tid & 3;
        x0[(n0 + jd) * 4 + q] = (q < 3) ? xs[(n0 + jd) * 3 + q] : 0.f;
    }
    __syncthreads();
    {
        const float4* hn = (const float4*)&sh[nl][0];
        const float4 h0q = hn[0], h1q = hn[1], h2q = hn[2], h3q = hn[3];
        float u = 0.f, v = sb1[k];
#pragma unroll
        for (int q = 0; q < 4; ++q) {
            const float4 hq = (q == 0) ? h0q : (q == 1) ? h1q : (q == 2) ? h2q : h3q;
            u = fmaf(hq.x, sWs[(4 * q + 0) * NF + k], u);
            u = fmaf(hq.y, sWs[(4 * q + 1) * NF + k], u);
            u = fmaf(hq.z, sWs[(4 * q + 2) * NF + k], u);
            u = fmaf(hq.w, sWs[(4 * q + 3) * NF + k], u);
            v = fmaf(hq.x, sWd[(4 * q + 0) * NF + k], v);
            v = fmaf(hq.y, sWd[(4 * q + 1) * NF + k], v);
            v = fmaf(hq.z, sWd[(4 * q + 2) * NF + k], v);
            v = fmaf(hq.w, sWd[(4 * q + 3) * NF + k], v);
        }
        su0[(n0 + nl) * NF + k] = u;
        sv0[(n0 + nl) * NF + k] = v;
    }
}

// R14: R8 structure, but the per-tile streams (su_b 16KB, x_b 4KB) are staged
// into LDS once per block (all 4 waves read the identical stream; previously
// each wave re-fetched every tile from L2/L3 written by scattered XCDs —
// latency-bound, implied VALUBusy ~15%). Tile reads become ds_read_b128:
// wave lanes (g,c) cover a contiguous 1KB slab of sSU => conflict-free;
// sX is 16 slots x 4-way broadcast => free. be2 folded into MFMA C operand
// (C-frag row = 4g+r matches be2f exactly), deleting 8 VALU adds/tile.
// LDS: 20KB streams + ~5.2KB tables = ~25.2KB/block; occupancy still
// VGPR-limited at 4 blocks/CU (16 waves/CU), unchanged.
__global__ __launch_bounds__(256)
void layer_kernel(const float* __restrict__ x_in, const float* __restrict__ h_in,
                  const float* __restrict__ su_in, const float* __restrict__ sv_in,
                  float* __restrict__ x_out, float* __restrict__ h_out,
                  float* __restrict__ su_out, float* __restrict__ sv_out,
                  const float* __restrict__ vs, const float* __restrict__ Wv_l,
                  const float* __restrict__ We1_l, const float* __restrict__ We2_l,
                  const float* __restrict__ be2_l, const float* __restrict__ Wx_l,
                  const float* __restrict__ Wh1_l, const float* __restrict__ bh1_l,
                  const float* __restrict__ We1_n, const float* __restrict__ be1_n,
                  int final_layer) {
    __shared__ __align__(16) float sSU[NN * NF];   // 16 KB: su_b staged
    __shared__ __align__(16) float sX[NN * 4];     // 4 KB: x_b staged (padded stride 4)
    __shared__ float sWh1s[512];
    __shared__ float sWa[256];            // next-layer WsrcT
    __shared__ float sWb[256];            // next-layer WdstT
    __shared__ float sbe1n[NF];
    __shared__ float sh_new[8][NF + 1];
    __shared__ float sg[8][NF];

    const int tid  = threadIdx.x;
    const int b    = blockIdx.x >> 5;
    const int oct  = blockIdx.x & 31;
    const int n0l  = 8 * oct;
    const size_t n0 = (size_t)b * NN + n0l;
    const int w    = tid >> 6;
    const int lane = tid & 63;
    const int c    = lane & 15;
    const int g    = lane >> 4;

    // stage epilogue/next-layer weights (consumed only after the post-loop sync)
    sWh1s[tid]       = Wh1_l[tid];
    sWh1s[256 + tid] = Wh1_l[256 + tid];
    if (!final_layer) {
        const int f = tid >> 4, k = tid & 15;
        sWa[k * NF + f] = We1_n[tid];           // WsrcT
        sWb[k * NF + f] = We1_n[256 + tid];     // WdstT
        if (tid < NF) sbe1n[tid] = be1_n[tid];
    }

    // stage the shared per-block streams: su_b (4096 f) and x_b (1024 f)
    {
        const float4* gsu = (const float4*)(su_in + (size_t)b * NN * NF);
        float4* lsu = (float4*)sSU;
        lsu[tid]        = gsu[tid];
        lsu[256 + tid]  = gsu[256 + tid];
        lsu[512 + tid]  = gsu[512 + tid];
        lsu[768 + tid]  = gsu[768 + tid];
        const float4* gx = (const float4*)(x_in + (size_t)b * NN * 4);
        ((float4*)sX)[tid] = gx[tid];
    }
    __syncthreads();

    // per-wave invariants for dsts j0, j1
    const int j0 = n0l + w, j1 = n0l + 4 + w;
    const float4 xj0 = *(const float4*)&sX[4 * j0];
    const float4 xj1 = *(const float4*)&sX[4 * j1];
    half4 afrag;
    afrag.x = (_Float16)We2_l[(4 * g + 0) * NF + c];
    afrag.y = (_Float16)We2_l[(4 * g + 1) * NF + c];
    afrag.z = (_Float16)We2_l[(4 * g + 2) * NF + c];
    afrag.w = (_Float16)We2_l[(4 * g + 3) * NF + c];
    const float4 v40  = *(const float4*)(sv_in + ((size_t)b * NN + j0) * NF + 4 * g);
    const float4 v41  = *(const float4*)(sv_in + ((size_t)b * NN + j1) * NF + 4 * g);
    const float4 wr4  = *(const float4*)(We1_l + 512 + 4 * g);
    const float4 be2f = *(const float4*)(be2_l + 4 * g);
    const float4 wxf  = *(const float4*)(Wx_l + 4 * g);
    f32x4 cb;
    cb.x = be2f.x; cb.y = be2f.y; cb.z = be2f.z; cb.w = be2f.w;

    float Sw0 = 0.f, Swx0 = 0.f, Swy0 = 0.f, Swz0 = 0.f;
    float Sw1 = 0.f, Swx1 = 0.f, Swy1 = 0.f, Swz1 = 0.f;
    float g00 = 0.f, g01 = 0.f, g02 = 0.f, g03 = 0.f;
    float g10 = 0.f, g11 = 0.f, g12 = 0.f, g13 = 0.f;

    const float* su_l = &sSU[c * NF + 4 * g];   // +256 floats per tile
    const float* x_l  = &sX[4 * c];             // +64 floats per tile

#pragma unroll 2
    for (int t = 0; t < 16; ++t) {
        const float4 u4  = *(const float4*)(su_l + 256 * t);
        const float4 xs4 = *(const float4*)(x_l + 64 * t);
        const int s = 16 * t + c;
        // ---- dst 0 ----
        {
            const float dx = xj0.x - xs4.x, dy = xj0.y - xs4.y, dz = xj0.z - xs4.z;
            const float r2 = fmaf(dx, dx, fmaf(dy, dy, dz * dz));
            const float m0 = fmaxf(fmaf(r2, wr4.x, u4.x + v40.x), 0.f);
            const float m1 = fmaxf(fmaf(r2, wr4.y, u4.y + v40.y), 0.f);
            const float m2 = fmaxf(fmaf(r2, wr4.z, u4.z + v40.z), 0.f);
            const float m3 = fmaxf(fmaf(r2, wr4.w, u4.w + v40.w), 0.f);
            half4 bfrag;
            bfrag.x = (_Float16)m0; bfrag.y = (_Float16)m1;
            bfrag.z = (_Float16)m2; bfrag.w = (_Float16)m3;
            const f32x4 acc = __builtin_amdgcn_mfma_f32_16x16x16f16(afrag, bfrag, cb, 0, 0, 0);
            const float e0 = fmaxf(acc.x, 0.f);
            const float e1 = fmaxf(acc.y, 0.f);
            const float e2 = fmaxf(acc.z, 0.f);
            const float e3 = fmaxf(acc.w, 0.f);
            float wp = e0 * wxf.x;
            wp = fmaf(e1, wxf.y, wp);
            wp = fmaf(e2, wxf.z, wp);
            wp = fmaf(e3, wxf.w, wp);
            const float gsel = (s != j0) ? 1.f : 0.f;
            g00 = fmaf(e0, gsel, g00);
            g01 = fmaf(e1, gsel, g01);
            g02 = fmaf(e2, gsel, g02);
            g03 = fmaf(e3, gsel, g03);
            Sw0 += wp;
            Swx0 = fmaf(wp, xs4.x, Swx0);
            Swy0 = fmaf(wp, xs4.y, Swy0);
            Swz0 = fmaf(wp, xs4.z, Swz0);
        }
        // ---- dst 1 (reuses u4/xs4) ----
        {
            const float dx = xj1.x - xs4.x, dy = xj1.y - xs4.y, dz = xj1.z - xs4.z;
            const float r2 = fmaf(dx, dx, fmaf(dy, dy, dz * dz));
            const float m0 = fmaxf(fmaf(r2, wr4.x, u4.x + v41.x), 0.f);
            const float m1 = fmaxf(fmaf(r2, wr4.y, u4.y + v41.y), 0.f);
            const float m2 = fmaxf(fmaf(r2, wr4.z, u4.z + v41.z), 0.f);
            const float m3 = fmaxf(fmaf(r2, wr4.w, u4.w + v41.w), 0.f);
            half4 bfrag;
            bfrag.x = (_Float16)m0; bfrag.y = (_Float16)m1;
            bfrag.z = (_Float16)m2; bfrag.w = (_Float16)m3;
            const f32x4 acc = __builtin_amdgcn_mfma_f32_16x16x16f16(afrag, bfrag, cb, 0, 0, 0);
            const float e0 = fmaxf(acc.x, 0.f);
            const float e1 = fmaxf(acc.y, 0.f);
            const float e2 = fmaxf(acc.z, 0.f);
            const float e3 = fmaxf(acc.w, 0.f);
            float wp = e0 * wxf.x;
            wp = fmaf(e1, wxf.y, wp);
            wp = fmaf(e2, wxf.z, wp);
            wp = fmaf(e3, wxf.w, wp);
            const float gsel = (s != j1) ? 1.f : 0.f;
            g10 = fmaf(e0, gsel, g10);
            g11 = fmaf(e1, gsel, g11);
            g12 = fmaf(e2, gsel, g12);
            g13 = fmaf(e3, gsel, g13);
            Sw1 += wp;
            Swx1 = fmaf(wp, xs4.x, Swx1);
            Swy1 = fmaf(wp, xs4.y, Swy1);
            Swz1 = fmaf(wp, xs4.z, Swz1);
        }
    }

    // ---- out-of-loop reductions ----
#pragma unroll
    for (int off = 1; off < 64; off <<= 1) {
        Sw0  += __shfl_xor(Sw0,  off, 64);  Sw1  += __shfl_xor(Sw1,  off, 64);
        Swx0 += __shfl_xor(Swx0, off, 64);  Swx1 += __shfl_xor(Swx1, off, 64);
        Swy0 += __shfl_xor(Swy0, off, 64);  Swy1 += __shfl_xor(Swy1, off, 64);
        Swz0 += __shfl_xor(Swz0, off, 64);  Swz1 += __shfl_xor(Swz1, off, 64);
    }
#pragma unroll
    for (int off = 1; off < 16; off <<= 1) {
        g00 += __shfl_xor(g00, off, 64);  g10 += __shfl_xor(g10, off, 64);
        g01 += __shfl_xor(g01, off, 64);  g11 += __shfl_xor(g11, off, 64);
        g02 += __shfl_xor(g02, off, 64);  g12 += __shfl_xor(g12, off, 64);
        g03 += __shfl_xor(g03, off, 64);  g13 += __shfl_xor(g13, off, 64);
    }
    if ((lane & 15) == 0) {
        *(float4*)&sg[w][4 * g]     = make_float4(g00, g01, g02, g03);
        *(float4*)&sg[w + 4][4 * g] = make_float4(g10, g11, g12, g13);
    }
    __syncthreads();

    // node epilogue: lanes 0..15 -> j0 (slot w); lanes 32..47 -> j1 (slot w+4)
    const int is0 = (lane < 16);
    const int is1 = (lane >= 32 && lane < 48);
    if (is0 || is1) {
        const int f = lane & 15;
        const int slot = is0 ? w : (w + 4);
        const int jm   = is0 ? j0 : j1;
        const float SwS = is0 ? Sw0  : Sw1;
        const float SxS = is0 ? Swx0 : Swx1;
        const float SyS = is0 ? Swy0 : Swy1;
        const float SzS = is0 ? Swz0 : Swz1;
        const float4 xjm = is0 ? xj0 : xj1;
        const size_t nj = (size_t)b * NN + jm;
        float hd = bh1_l[f];
        float hv = 0.f;
#pragma unroll
        for (int k = 0; k < NF; ++k) {
            const float hjk = h_in[nj * NF + k];
            hd = fmaf(hjk, sWh1s[k * NF + f], hd);
            hv = fmaf(hjk, Wv_l[k], hv);
        }
#pragma unroll
        for (int k = 0; k < NF; ++k) {
            hd = fmaf(sg[slot][k], sWh1s[(NF + k) * NF + f], hd);
        }
        const float hnew = h_in[nj * NF + f] + fmaxf(hd, 0.f);
        sh_new[slot][f] = hnew;
        if (!final_layer) h_out[nj * NF + f] = hnew;
        if (f < 3) {
            const float xc = (f == 0) ? xjm.x : ((f == 1) ? xjm.y : xjm.z);
            const float Sc = (f == 0) ? SxS  : ((f == 1) ? SyS  : SzS);
            const float agg = (SwS * xc - Sc) * (1.f / 255.f);
            const float xnew = xc + agg + vs[nj * 3 + f] * hv;
            if (final_layer) x_out[nj * 3 + f] = xnew;
            else             x_out[nj * 4 + f] = xnew;
        }
        if (!final_layer && f == 3) x_out[nj * 4 + 3] = 0.f;
    }

    if (!final_layer) {
        __syncthreads();
        // su/sv for the NEXT layer (this block's 8 nodes)
        if (tid < 128) {
            const int jd = tid >> 4, k = tid & 15;
            float u = 0.f, v = sbe1n[k];
#pragma unroll
            for (int f = 0; f < NF; ++f) {
                const float hf = sh_new[jd][f];
                u = fmaf(hf, sWa[k * NF + f], u);
                v = fmaf(hf, sWb[k * NF + f], v);
            }
            su_out[(n0 + jd) * NF + k] = u;
            sv_out[(n0 + jd) * NF + k] = v;
        }
    }
}

extern "C" void kernel_launch(void* const* d_in, const int* in_sizes, int n_in,
                              void* d_out, int out_size, void* d_ws, size_t ws_size,
                              hipStream_t stream) {
    const float* xs      = (const float*)d_in[0];
    const float* vs      = (const float*)d_in[1];
    const float* charges = (const float*)d_in[2];
    const float* W_in    = (const float*)d_in[3];
    const float* b_in    = (const float*)d_in[4];
    const float* W_v     = (const float*)d_in[5];
    const float* We1     = (const float*)d_in[6];
    const float* be1     = (const float*)d_in[7];
    const float* We2     = (const float*)d_in[8];
    const float* be2     = (const float*)d_in[9];
    const float* Wx      = (const float*)d_in[10];
    const float* Wh1     = (const float*)d_in[11];
    const float* bh1     = (const float*)d_in[12];
    // d_in[13]=src, d_in[14]=dst: fully-connected pattern, computed analytically.

    float* ws = (float*)d_ws;
    float* x0  = ws + X0_OFF;
    float* x1  = ws + X1_OFF;
    float* h0  = ws + H0_OFF;
    float* h1  = ws + H1_OFF;
    float* su0 = ws + SU0_OFF;
    float* sv0 = ws + SV0_OFF;
    float* su1 = ws + SU1_OFF;
    float* sv1 = ws + SV1_OFF;
    float* su2 = ws + SU2_OFF;
    float* sv2 = ws + SV2_OFF;
    float* out = (float*)d_out;

    hipLaunchKernelGGL(init_kernel, dim3(512), dim3(256), 0, stream,
                       xs, charges, W_in, b_in, We1, be1, x0, h0, su0, sv0);
    hipLaunchKernelGGL(layer_kernel, dim3(1024), dim3(256), 0, stream,
                       x0, h0, su0, sv0, x1, h1, su1, sv1,
                       vs, W_v + 0 * 16, We1 + 0 * 528, We2 + 0 * 256,
                       be2 + 0 * 16, Wx + 0 * 16, Wh1 + 0 * 512, bh1 + 0 * 16,
                       We1 + 1 * 528, be1 + 1 * 16, 0);
    hipLaunchKernelGGL(layer_kernel, dim3(1024), dim3(256), 0, stream,
                       x1, h1, su1, sv1, x0, h0, su2, sv2,
                       vs, W_v + 1 * 16, We1 + 1 * 528, We2 + 1 * 256,
                       be2 + 1 * 16, Wx + 1 * 16, Wh1 + 1 * 512, bh1 + 1 * 16,
                       We1 + 2 * 528, be1 + 2 * 16, 0);
    hipLaunchKernelGGL(layer_kernel, dim3(1024), dim3(256), 0, stream,
                       x0, h0, su2, sv2, out, h1, su1, sv1,
                       vs, W_v + 2 * 16, We1 + 2 * 528, We2 + 2 * 256,
                       be2 + 2 * 16, Wx + 2 * 16, Wh1 + 2 * 512, bh1 + 2 * 16,
                       We1 + 2 * 528, be1 + 2 * 16, 1);
}

// Round 3
// 131.833 us; speedup vs baseline: 1.0226x; 1.0070x over previous
//
#include <hip/hip_runtime.h>

#define NN 256
#define NF 16

typedef _Float16 half4 __attribute__((ext_vector_type(4)));
typedef float f32x4 __attribute__((ext_vector_type(4)));

// ws layout (floats): ping-pong x/h/su/sv
#define XA_OFF 0
#define XB_OFF 32768
#define HA_OFF 65536
#define HB_OFF 196608
#define SUA_OFF 327680
#define SVA_OFF 458752
#define SUB_OFF 589824
#define SVB_OFF 720896

// R16: layer0_kernel = R15's block-local init fused with the R8/R14 layer-0
// body. All layer-0 inputs (h0, su0, sv0, x0) are computed in-block from
// charges/xs (su0 for the full batch redundantly per block: 256 FMA/thr),
// so NO cross-block data and NO init dispatch. Layers 1/2 remain the proven
// R14 kernel verbatim; kernel boundaries provide the device-wide sync +
// cache flush that R15's grid.sync() appears NOT to guarantee across XCDs
// (R15 failed absmax=480 with stale-read signature; within-block ordering
// was verified line-by-line).
__global__ __launch_bounds__(256)
void layer0_kernel(const float* __restrict__ xs, const float* __restrict__ vs,
                   const float* __restrict__ charges,
                   const float* __restrict__ W_in, const float* __restrict__ b_in,
                   const float* __restrict__ W_v, const float* __restrict__ We1_l,
                   const float* __restrict__ be1_l, const float* __restrict__ We2_l,
                   const float* __restrict__ be2_l, const float* __restrict__ Wx_l,
                   const float* __restrict__ Wh1_l, const float* __restrict__ bh1_l,
                   const float* __restrict__ We1_n, const float* __restrict__ be1_n,
                   float* __restrict__ x_out, float* __restrict__ h_out,
                   float* __restrict__ su_out, float* __restrict__ sv_out) {
    __shared__ __align__(16) float sSU[NN * NF];   // 16 KB: su0 (this batch)
    __shared__ __align__(16) float sX[NN * 4];     // 4 KB: x0 padded
    __shared__ __align__(16) float sHg[64 * NF];   // 4 KB: init scratch
    __shared__ float sWs[256], sWd[256];           // L0 We1 src/dst
    __shared__ __align__(16) float sSV8[8][NF];    // own-octet sv0
    __shared__ __align__(16) float sH8[8][NF + 1]; // own-octet h0
    __shared__ float sWh1s[512];
    __shared__ float sWa[256], sWb[256];           // next-layer We1^T
    __shared__ float sbe1n[NF];
    __shared__ float sh_new[8][NF + 1];
    __shared__ float sg[8][NF];

    const int tid  = threadIdx.x;
    const int b    = blockIdx.x >> 5;
    const int oct  = blockIdx.x & 31;
    const int n0l  = 8 * oct;
    const size_t n0 = (size_t)b * NN + n0l;
    const int w    = tid >> 6;
    const int lane = tid & 63;
    const int c    = lane & 15;
    const int g    = lane >> 4;

    // ---- stage all weights + x (no cross-block data anywhere) ----
    sWs[tid] = We1_l[tid];          // L0 src rows [f][k]
    sWd[tid] = We1_l[256 + tid];    // L0 dst rows [f][k]
    sWh1s[tid]       = Wh1_l[tid];
    sWh1s[256 + tid] = Wh1_l[256 + tid];
    {
        const int f = tid >> 4, kk = tid & 15;
        sWa[kk * NF + f] = We1_n[tid];           // next-layer WsrcT
        sWb[kk * NF + f] = We1_n[256 + tid];     // next-layer WdstT
        if (tid < NF) sbe1n[tid] = be1_n[tid];
    }
    {   // x0 padded stride-4 from xs stride-3
        const size_t base = ((size_t)b * NN + tid) * 3;
        sX[tid * 4 + 0] = xs[base + 0];
        sX[tid * 4 + 1] = xs[base + 1];
        sX[tid * 4 + 2] = xs[base + 2];
        sX[tid * 4 + 3] = 0.f;
    }

    // ---- init: h0 (own octet), su0 (all 256 nodes), sv0 (own octet) ----
    const int nl = tid >> 4, k = tid & 15;
    const float win  = W_in[k];
    const float bin  = b_in[k];
    const float be1k = be1_l[k];
    const int i0 = n0l >> 6;              // 64-node group holding our octet
    const int r0 = (n0l & 63) >> 4;       // 16-row within group
    const int halfsel = (n0l >> 3) & 1;   // 8-half within the 16-row
    const int own = ((nl >> 3) == halfsel);
#pragma unroll
    for (int i = 0; i < 4; ++i) {
        // phase A: h = relu(c*W_in + b_in) for nodes 64i .. 64i+63
#pragma unroll
        for (int r = 0; r < 4; ++r) {
            const float cq = charges[(size_t)b * NN + 64 * i + 16 * r + nl];
            const float hf = fmaxf(fmaf(cq, win, bin), 0.f);
            sHg[(16 * r + nl) * NF + k] = hf;
            if (i == i0 && r == r0 && own) sH8[nl & 7][k] = hf;
        }
        __syncthreads();
        // phase B: su0 = h @ Wsrc for these 64 nodes (+ own sv0)
#pragma unroll
        for (int r = 0; r < 4; ++r) {
            const float4* hn = (const float4*)&sHg[(16 * r + nl) * NF];
            const float4 h0q = hn[0], h1q = hn[1], h2q = hn[2], h3q = hn[3];
            float u = 0.f;
#pragma unroll
            for (int q = 0; q < 4; ++q) {
                const float4 hq = (q == 0) ? h0q : (q == 1) ? h1q : (q == 2) ? h2q : h3q;
                u = fmaf(hq.x, sWs[(4 * q + 0) * NF + k], u);
                u = fmaf(hq.y, sWs[(4 * q + 1) * NF + k], u);
                u = fmaf(hq.z, sWs[(4 * q + 2) * NF + k], u);
                u = fmaf(hq.w, sWs[(4 * q + 3) * NF + k], u);
            }
            sSU[(64 * i + 16 * r + nl) * NF + k] = u;
            if (i == i0 && r == r0 && own) {
                float v = be1k;
#pragma unroll
                for (int q = 0; q < 4; ++q) {
                    const float4 hq = (q == 0) ? h0q : (q == 1) ? h1q : (q == 2) ? h2q : h3q;
                    v = fmaf(hq.x, sWd[(4 * q + 0) * NF + k], v);
                    v = fmaf(hq.y, sWd[(4 * q + 1) * NF + k], v);
                    v = fmaf(hq.z, sWd[(4 * q + 2) * NF + k], v);
                    v = fmaf(hq.w, sWd[(4 * q + 3) * NF + k], v);
                }
                sSV8[nl & 7][k] = v;
            }
        }
        __syncthreads();
    }

    // ---- layer-0 body (R14 structure; inputs all LDS-local) ----
    const int j0 = n0l + w, j1 = n0l + 4 + w;
    const float4 xj0 = *(const float4*)&sX[4 * j0];
    const float4 xj1 = *(const float4*)&sX[4 * j1];
    half4 afrag;
    afrag.x = (_Float16)We2_l[(4 * g + 0) * NF + c];
    afrag.y = (_Float16)We2_l[(4 * g + 1) * NF + c];
    afrag.z = (_Float16)We2_l[(4 * g + 2) * NF + c];
    afrag.w = (_Float16)We2_l[(4 * g + 3) * NF + c];
    const float4 v40 = *(const float4*)&sSV8[w][4 * g];
    const float4 v41 = *(const float4*)&sSV8[4 + w][4 * g];
    const float4 wr4  = *(const float4*)(We1_l + 512 + 4 * g);
    const float4 be2f = *(const float4*)(be2_l + 4 * g);
    const float4 wxf  = *(const float4*)(Wx_l + 4 * g);
    f32x4 cb;
    cb.x = be2f.x; cb.y = be2f.y; cb.z = be2f.z; cb.w = be2f.w;

    float Sw0 = 0.f, Swx0 = 0.f, Swy0 = 0.f, Swz0 = 0.f;
    float Sw1 = 0.f, Swx1 = 0.f, Swy1 = 0.f, Swz1 = 0.f;
    float g00 = 0.f, g01 = 0.f, g02 = 0.f, g03 = 0.f;
    float g10 = 0.f, g11 = 0.f, g12 = 0.f, g13 = 0.f;

    const float* su_l = &sSU[c * NF + 4 * g];
    const float* x_l  = &sX[4 * c];

#pragma unroll 2
    for (int t = 0; t < 16; ++t) {
        const float4 u4  = *(const float4*)(su_l + 256 * t);
        const float4 xs4 = *(const float4*)(x_l + 64 * t);
        const int s = 16 * t + c;
        {
            const float dx = xj0.x - xs4.x, dy = xj0.y - xs4.y, dz = xj0.z - xs4.z;
            const float r2 = fmaf(dx, dx, fmaf(dy, dy, dz * dz));
            const float m0 = fmaxf(fmaf(r2, wr4.x, u4.x + v40.x), 0.f);
            const float m1 = fmaxf(fmaf(r2, wr4.y, u4.y + v40.y), 0.f);
            const float m2 = fmaxf(fmaf(r2, wr4.z, u4.z + v40.z), 0.f);
            const float m3 = fmaxf(fmaf(r2, wr4.w, u4.w + v40.w), 0.f);
            half4 bfrag;
            bfrag.x = (_Float16)m0; bfrag.y = (_Float16)m1;
            bfrag.z = (_Float16)m2; bfrag.w = (_Float16)m3;
            const f32x4 acc = __builtin_amdgcn_mfma_f32_16x16x16f16(afrag, bfrag, cb, 0, 0, 0);
            const float e0 = fmaxf(acc.x, 0.f);
            const float e1 = fmaxf(acc.y, 0.f);
            const float e2 = fmaxf(acc.z, 0.f);
            const float e3 = fmaxf(acc.w, 0.f);
            float wp = e0 * wxf.x;
            wp = fmaf(e1, wxf.y, wp);
            wp = fmaf(e2, wxf.z, wp);
            wp = fmaf(e3, wxf.w, wp);
            const float gsel = (s != j0) ? 1.f : 0.f;
            g00 = fmaf(e0, gsel, g00);
            g01 = fmaf(e1, gsel, g01);
            g02 = fmaf(e2, gsel, g02);
            g03 = fmaf(e3, gsel, g03);
            Sw0 += wp;
            Swx0 = fmaf(wp, xs4.x, Swx0);
            Swy0 = fmaf(wp, xs4.y, Swy0);
            Swz0 = fmaf(wp, xs4.z, Swz0);
        }
        {
            const float dx = xj1.x - xs4.x, dy = xj1.y - xs4.y, dz = xj1.z - xs4.z;
            const float r2 = fmaf(dx, dx, fmaf(dy, dy, dz * dz));
            const float m0 = fmaxf(fmaf(r2, wr4.x, u4.x + v41.x), 0.f);
            const float m1 = fmaxf(fmaf(r2, wr4.y, u4.y + v41.y), 0.f);
            const float m2 = fmaxf(fmaf(r2, wr4.z, u4.z + v41.z), 0.f);
            const float m3 = fmaxf(fmaf(r2, wr4.w, u4.w + v41.w), 0.f);
            half4 bfrag;
            bfrag.x = (_Float16)m0; bfrag.y = (_Float16)m1;
            bfrag.z = (_Float16)m2; bfrag.w = (_Float16)m3;
            const f32x4 acc = __builtin_amdgcn_mfma_f32_16x16x16f16(afrag, bfrag, cb, 0, 0, 0);
            const float e0 = fmaxf(acc.x, 0.f);
            const float e1 = fmaxf(acc.y, 0.f);
            const float e2 = fmaxf(acc.z, 0.f);
            const float e3 = fmaxf(acc.w, 0.f);
            float wp = e0 * wxf.x;
            wp = fmaf(e1, wxf.y, wp);
            wp = fmaf(e2, wxf.z, wp);
            wp = fmaf(e3, wxf.w, wp);
            const float gsel = (s != j1) ? 1.f : 0.f;
            g10 = fmaf(e0, gsel, g10);
            g11 = fmaf(e1, gsel, g11);
            g12 = fmaf(e2, gsel, g12);
            g13 = fmaf(e3, gsel, g13);
            Sw1 += wp;
            Swx1 = fmaf(wp, xs4.x, Swx1);
            Swy1 = fmaf(wp, xs4.y, Swy1);
            Swz1 = fmaf(wp, xs4.z, Swz1);
        }
    }

#pragma unroll
    for (int off = 1; off < 64; off <<= 1) {
        Sw0  += __shfl_xor(Sw0,  off, 64);  Sw1  += __shfl_xor(Sw1,  off, 64);
        Swx0 += __shfl_xor(Swx0, off, 64);  Swx1 += __shfl_xor(Swx1, off, 64);
        Swy0 += __shfl_xor(Swy0, off, 64);  Swy1 += __shfl_xor(Swy1, off, 64);
        Swz0 += __shfl_xor(Swz0, off, 64);  Swz1 += __shfl_xor(Swz1, off, 64);
    }
#pragma unroll
    for (int off = 1; off < 16; off <<= 1) {
        g00 += __shfl_xor(g00, off, 64);  g10 += __shfl_xor(g10, off, 64);
        g01 += __shfl_xor(g01, off, 64);  g11 += __shfl_xor(g11, off, 64);
        g02 += __shfl_xor(g02, off, 64);  g12 += __shfl_xor(g12, off, 64);
        g03 += __shfl_xor(g03, off, 64);  g13 += __shfl_xor(g13, off, 64);
    }
    if ((lane & 15) == 0) {
        *(float4*)&sg[w][4 * g]     = make_float4(g00, g01, g02, g03);
        *(float4*)&sg[w + 4][4 * g] = make_float4(g10, g11, g12, g13);
    }
    __syncthreads();

    const int is0 = (lane < 16);
    const int is1 = (lane >= 32 && lane < 48);
    if (is0 || is1) {
        const int f = lane & 15;
        const int slot = is0 ? w : (w + 4);
        const int jm   = is0 ? j0 : j1;
        const float SwS = is0 ? Sw0  : Sw1;
        const float SxS = is0 ? Swx0 : Swx1;
        const float SyS = is0 ? Swy0 : Swy1;
        const float SzS = is0 ? Swz0 : Swz1;
        const float4 xjm = is0 ? xj0 : xj1;
        const size_t nj = (size_t)b * NN + jm;
        float hd = bh1_l[f];
        float hv = 0.f;
#pragma unroll
        for (int kk = 0; kk < NF; ++kk) {
            const float hjk = sH8[slot][kk];
            hd = fmaf(hjk, sWh1s[kk * NF + f], hd);
            hv = fmaf(hjk, W_v[kk], hv);
        }
#pragma unroll
        for (int kk = 0; kk < NF; ++kk) {
            hd = fmaf(sg[slot][kk], sWh1s[(NF + kk) * NF + f], hd);
        }
        const float hnew = sH8[slot][f] + fmaxf(hd, 0.f);
        sh_new[slot][f] = hnew;
        h_out[nj * NF + f] = hnew;
        if (f < 3) {
            const float xc = (f == 0) ? xjm.x : ((f == 1) ? xjm.y : xjm.z);
            const float Sc = (f == 0) ? SxS  : ((f == 1) ? SyS  : SzS);
            const float agg = (SwS * xc - Sc) * (1.f / 255.f);
            const float xnew = xc + agg + vs[nj * 3 + f] * hv;
            x_out[nj * 4 + f] = xnew;
        }
        if (f == 3) x_out[nj * 4 + 3] = 0.f;
    }

    __syncthreads();
    if (tid < 128) {
        const int jd = tid >> 4, kk = tid & 15;
        float u = 0.f, v = sbe1n[kk];
#pragma unroll
        for (int f = 0; f < NF; ++f) {
            const float hf = sh_new[jd][f];
            u = fmaf(hf, sWa[kk * NF + f], u);
            v = fmaf(hf, sWb[kk * NF + f], v);
        }
        su_out[(n0 + jd) * NF + kk] = u;
        sv_out[(n0 + jd) * NF + kk] = v;
    }
}

// R14 layer kernel VERBATIM (passed twice; LDS-staged streams + be2-in-C).
__global__ __launch_bounds__(256)
void layer_kernel(const float* __restrict__ x_in, const float* __restrict__ h_in,
                  const float* __restrict__ su_in, const float* __restrict__ sv_in,
                  float* __restrict__ x_out, float* __restrict__ h_out,
                  float* __restrict__ su_out, float* __restrict__ sv_out,
                  const float* __restrict__ vs, const float* __restrict__ Wv_l,
                  const float* __restrict__ We1_l, const float* __restrict__ We2_l,
                  const float* __restrict__ be2_l, const float* __restrict__ Wx_l,
                  const float* __restrict__ Wh1_l, const float* __restrict__ bh1_l,
                  const float* __restrict__ We1_n, const float* __restrict__ be1_n,
                  int final_layer) {
    __shared__ __align__(16) float sSU[NN * NF];
    __shared__ __align__(16) float sX[NN * 4];
    __shared__ float sWh1s[512];
    __shared__ float sWa[256];
    __shared__ float sWb[256];
    __shared__ float sbe1n[NF];
    __shared__ float sh_new[8][NF + 1];
    __shared__ float sg[8][NF];

    const int tid  = threadIdx.x;
    const int b    = blockIdx.x >> 5;
    const int oct  = blockIdx.x & 31;
    const int n0l  = 8 * oct;
    const size_t n0 = (size_t)b * NN + n0l;
    const int w    = tid >> 6;
    const int lane = tid & 63;
    const int c    = lane & 15;
    const int g    = lane >> 4;

    sWh1s[tid]       = Wh1_l[tid];
    sWh1s[256 + tid] = Wh1_l[256 + tid];
    if (!final_layer) {
        const int f = tid >> 4, k = tid & 15;
        sWa[k * NF + f] = We1_n[tid];
        sWb[k * NF + f] = We1_n[256 + tid];
        if (tid < NF) sbe1n[tid] = be1_n[tid];
    }
    {
        const float4* gsu = (const float4*)(su_in + (size_t)b * NN * NF);
        float4* lsu = (float4*)sSU;
        lsu[tid]        = gsu[tid];
        lsu[256 + tid]  = gsu[256 + tid];
        lsu[512 + tid]  = gsu[512 + tid];
        lsu[768 + tid]  = gsu[768 + tid];
        const float4* gx = (const float4*)(x_in + (size_t)b * NN * 4);
        ((float4*)sX)[tid] = gx[tid];
    }
    __syncthreads();

    const int j0 = n0l + w, j1 = n0l + 4 + w;
    const float4 xj0 = *(const float4*)&sX[4 * j0];
    const float4 xj1 = *(const float4*)&sX[4 * j1];
    half4 afrag;
    afrag.x = (_Float16)We2_l[(4 * g + 0) * NF + c];
    afrag.y = (_Float16)We2_l[(4 * g + 1) * NF + c];
    afrag.z = (_Float16)We2_l[(4 * g + 2) * NF + c];
    afrag.w = (_Float16)We2_l[(4 * g + 3) * NF + c];
    const float4 v40  = *(const float4*)(sv_in + ((size_t)b * NN + j0) * NF + 4 * g);
    const float4 v41  = *(const float4*)(sv_in + ((size_t)b * NN + j1) * NF + 4 * g);
    const float4 wr4  = *(const float4*)(We1_l + 512 + 4 * g);
    const float4 be2f = *(const float4*)(be2_l + 4 * g);
    const float4 wxf  = *(const float4*)(Wx_l + 4 * g);
    f32x4 cb;
    cb.x = be2f.x; cb.y = be2f.y; cb.z = be2f.z; cb.w = be2f.w;

    float Sw0 = 0.f, Swx0 = 0.f, Swy0 = 0.f, Swz0 = 0.f;
    float Sw1 = 0.f, Swx1 = 0.f, Swy1 = 0.f, Swz1 = 0.f;
    float g00 = 0.f, g01 = 0.f, g02 = 0.f, g03 = 0.f;
    float g10 = 0.f, g11 = 0.f, g12 = 0.f, g13 = 0.f;

    const float* su_l = &sSU[c * NF + 4 * g];
    const float* x_l  = &sX[4 * c];

#pragma unroll 2
    for (int t = 0; t < 16; ++t) {
        const float4 u4  = *(const float4*)(su_l + 256 * t);
        const float4 xs4 = *(const float4*)(x_l + 64 * t);
        const int s = 16 * t + c;
        {
            const float dx = xj0.x - xs4.x, dy = xj0.y - xs4.y, dz = xj0.z - xs4.z;
            const float r2 = fmaf(dx, dx, fmaf(dy, dy, dz * dz));
            const float m0 = fmaxf(fmaf(r2, wr4.x, u4.x + v40.x), 0.f);
            const float m1 = fmaxf(fmaf(r2, wr4.y, u4.y + v40.y), 0.f);
            const float m2 = fmaxf(fmaf(r2, wr4.z, u4.z + v40.z), 0.f);
            const float m3 = fmaxf(fmaf(r2, wr4.w, u4.w + v40.w), 0.f);
            half4 bfrag;
            bfrag.x = (_Float16)m0; bfrag.y = (_Float16)m1;
            bfrag.z = (_Float16)m2; bfrag.w = (_Float16)m3;
            const f32x4 acc = __builtin_amdgcn_mfma_f32_16x16x16f16(afrag, bfrag, cb, 0, 0, 0);
            const float e0 = fmaxf(acc.x, 0.f);
            const float e1 = fmaxf(acc.y, 0.f);
            const float e2 = fmaxf(acc.z, 0.f);
            const float e3 = fmaxf(acc.w, 0.f);
            float wp = e0 * wxf.x;
            wp = fmaf(e1, wxf.y, wp);
            wp = fmaf(e2, wxf.z, wp);
            wp = fmaf(e3, wxf.w, wp);
            const float gsel = (s != j0) ? 1.f : 0.f;
            g00 = fmaf(e0, gsel, g00);
            g01 = fmaf(e1, gsel, g01);
            g02 = fmaf(e2, gsel, g02);
            g03 = fmaf(e3, gsel, g03);
            Sw0 += wp;
            Swx0 = fmaf(wp, xs4.x, Swx0);
            Swy0 = fmaf(wp, xs4.y, Swy0);
            Swz0 = fmaf(wp, xs4.z, Swz0);
        }
        {
            const float dx = xj1.x - xs4.x, dy = xj1.y - xs4.y, dz = xj1.z - xs4.z;
            const float r2 = fmaf(dx, dx, fmaf(dy, dy, dz * dz));
            const float m0 = fmaxf(fmaf(r2, wr4.x, u4.x + v41.x), 0.f);
            const float m1 = fmaxf(fmaf(r2, wr4.y, u4.y + v41.y), 0.f);
            const float m2 = fmaxf(fmaf(r2, wr4.z, u4.z + v41.z), 0.f);
            const float m3 = fmaxf(fmaf(r2, wr4.w, u4.w + v41.w), 0.f);
            half4 bfrag;
            bfrag.x = (_Float16)m0; bfrag.y = (_Float16)m1;
            bfrag.z = (_Float16)m2; bfrag.w = (_Float16)m3;
            const f32x4 acc = __builtin_amdgcn_mfma_f32_16x16x16f16(afrag, bfrag, cb, 0, 0, 0);
            const float e0 = fmaxf(acc.x, 0.f);
            const float e1 = fmaxf(acc.y, 0.f);
            const float e2 = fmaxf(acc.z, 0.f);
            const float e3 = fmaxf(acc.w, 0.f);
            float wp = e0 * wxf.x;
            wp = fmaf(e1, wxf.y, wp);
            wp = fmaf(e2, wxf.z, wp);
            wp = fmaf(e3, wxf.w, wp);
            const float gsel = (s != j1) ? 1.f : 0.f;
            g10 = fmaf(e0, gsel, g10);
            g11 = fmaf(e1, gsel, g11);
            g12 = fmaf(e2, gsel, g12);
            g13 = fmaf(e3, gsel, g13);
            Sw1 += wp;
            Swx1 = fmaf(wp, xs4.x, Swx1);
            Swy1 = fmaf(wp, xs4.y, Swy1);
            Swz1 = fmaf(wp, xs4.z, Swz1);
        }
    }

#pragma unroll
    for (int off = 1; off < 64; off <<= 1) {
        Sw0  += __shfl_xor(Sw0,  off, 64);  Sw1  += __shfl_xor(Sw1,  off, 64);
        Swx0 += __shfl_xor(Swx0, off, 64);  Swx1 += __shfl_xor(Swx1, off, 64);
        Swy0 += __shfl_xor(Swy0, off, 64);  Swy1 += __shfl_xor(Swy1, off, 64);
        Swz0 += __shfl_xor(Swz0, off, 64);  Swz1 += __shfl_xor(Swz1, off, 64);
    }
#pragma unroll
    for (int off = 1; off < 16; off <<= 1) {
        g00 += __shfl_xor(g00, off, 64);  g10 += __shfl_xor(g10, off, 64);
        g01 += __shfl_xor(g01, off, 64);  g11 += __shfl_xor(g11, off, 64);
        g02 += __shfl_xor(g02, off, 64);  g12 += __shfl_xor(g12, off, 64);
        g03 += __shfl_xor(g03, off, 64);  g13 += __shfl_xor(g13, off, 64);
    }
    if ((lane & 15) == 0) {
        *(float4*)&sg[w][4 * g]     = make_float4(g00, g01, g02, g03);
        *(float4*)&sg[w + 4][4 * g] = make_float4(g10, g11, g12, g13);
    }
    __syncthreads();

    const int is0 = (lane < 16);
    const int is1 = (lane >= 32 && lane < 48);
    if (is0 || is1) {
        const int f = lane & 15;
        const int slot = is0 ? w : (w + 4);
        const int jm   = is0 ? j0 : j1;
        const float SwS = is0 ? Sw0  : Sw1;
        const float SxS = is0 ? Swx0 : Swx1;
        const float SyS = is0 ? Swy0 : Swy1;
        const float SzS = is0 ? Swz0 : Swz1;
        const float4 xjm = is0 ? xj0 : xj1;
        const size_t nj = (size_t)b * NN + jm;
        float hd = bh1_l[f];
        float hv = 0.f;
#pragma unroll
        for (int k = 0; k < NF; ++k) {
            const float hjk = h_in[nj * NF + k];
            hd = fmaf(hjk, sWh1s[k * NF + f], hd);
            hv = fmaf(hjk, Wv_l[k], hv);
        }
#pragma unroll
        for (int k = 0; k < NF; ++k) {
            hd = fmaf(sg[slot][k], sWh1s[(NF + k) * NF + f], hd);
        }
        const float hnew = h_in[nj * NF + f] + fmaxf(hd, 0.f);
        sh_new[slot][f] = hnew;
        if (!final_layer) h_out[nj * NF + f] = hnew;
        if (f < 3) {
            const float xc = (f == 0) ? xjm.x : ((f == 1) ? xjm.y : xjm.z);
            const float Sc = (f == 0) ? SxS  : ((f == 1) ? SyS  : SzS);
            const float agg = (SwS * xc - Sc) * (1.f / 255.f);
            const float xnew = xc + agg + vs[nj * 3 + f] * hv;
            if (final_layer) x_out[nj * 3 + f] = xnew;
            else             x_out[nj * 4 + f] = xnew;
        }
        if (!final_layer && f == 3) x_out[nj * 4 + 3] = 0.f;
    }

    if (!final_layer) {
        __syncthreads();
        if (tid < 128) {
            const int jd = tid >> 4, k = tid & 15;
            float u = 0.f, v = sbe1n[k];
#pragma unroll
            for (int f = 0; f < NF; ++f) {
                const float hf = sh_new[jd][f];
                u = fmaf(hf, sWa[k * NF + f], u);
                v = fmaf(hf, sWb[k * NF + f], v);
            }
            su_out[(n0 + jd) * NF + k] = u;
            sv_out[(n0 + jd) * NF + k] = v;
        }
    }
}

extern "C" void kernel_launch(void* const* d_in, const int* in_sizes, int n_in,
                              void* d_out, int out_size, void* d_ws, size_t ws_size,
                              hipStream_t stream) {
    const float* xs      = (const float*)d_in[0];
    const float* vs      = (const float*)d_in[1];
    const float* charges = (const float*)d_in[2];
    const float* W_in    = (const float*)d_in[3];
    const float* b_in    = (const float*)d_in[4];
    const float* W_v     = (const float*)d_in[5];
    const float* We1     = (const float*)d_in[6];
    const float* be1     = (const float*)d_in[7];
    const float* We2     = (const float*)d_in[8];
    const float* be2     = (const float*)d_in[9];
    const float* Wx      = (const float*)d_in[10];
    const float* Wh1     = (const float*)d_in[11];
    const float* bh1     = (const float*)d_in[12];
    // d_in[13]=src, d_in[14]=dst: fully-connected pattern, computed analytically.

    float* ws = (float*)d_ws;
    float* xA  = ws + XA_OFF;
    float* xB  = ws + XB_OFF;
    float* hA  = ws + HA_OFF;
    float* hB  = ws + HB_OFF;
    float* suA = ws + SUA_OFF;
    float* svA = ws + SVA_OFF;
    float* suB = ws + SUB_OFF;
    float* svB = ws + SVB_OFF;
    float* out = (float*)d_out;

    // L0 (init fused): writes x1->xA, h1->hA, su1->suA, sv1->svA
    hipLaunchKernelGGL(layer0_kernel, dim3(1024), dim3(256), 0, stream,
                       xs, vs, charges, W_in, b_in,
                       W_v + 0 * 16, We1 + 0 * 528, be1 + 0 * 16, We2 + 0 * 256,
                       be2 + 0 * 16, Wx + 0 * 16, Wh1 + 0 * 512, bh1 + 0 * 16,
                       We1 + 1 * 528, be1 + 1 * 16,
                       xA, hA, suA, svA);
    // L1
    hipLaunchKernelGGL(layer_kernel, dim3(1024), dim3(256), 0, stream,
                       xA, hA, suA, svA, xB, hB, suB, svB,
                       vs, W_v + 1 * 16, We1 + 1 * 528, We2 + 1 * 256,
                       be2 + 1 * 16, Wx + 1 * 16, Wh1 + 1 * 512, bh1 + 1 * 16,
                       We1 + 2 * 528, be1 + 2 * 16, 0);
    // L2 (final)
    hipLaunchKernelGGL(layer_kernel, dim3(1024), dim3(256), 0, stream,
                       xB, hB, suB, svB, out, hA, suA, svA,
                       vs, W_v + 2 * 16, We1 + 2 * 528, We2 + 2 * 256,
                       be2 + 2 * 16, Wx + 2 * 16, Wh1 + 2 * 512, bh1 + 2 * 16,
                       We1 + 2 * 528, be1 + 2 * 16, 1);
}